// Round 4
// baseline (80.953 us; speedup 1.0000x reference)
//
#include <hip/hip_runtime.h>

// Laplace attention: unnorm[b,i,j] = sum_d |k[b,j,d] - v[b,i,d]| * 0.5
//                    W = softmax_j(unnorm);  out = W @ v[b]
// B=8, M=512, D=64, fp32. q unused. No max-subtraction needed (dist ~36+-3.4,
// exp fp32-safe) -> cross-slice combine is purely additive.
//
// k1 design (register-resident, uniform-operand):
//   lane = output row i. Lane holds v_i[64] (own V row) and acc[64] in VGPRs.
//   Per j: k[j][:] and v[j][:] are WAVE-UNIFORM rows -> compiler emits s_load
//   (SGPR operands for v_sub/v_fmac); inner loop has NO LDS and NO per-lane
//   VMEM. 128 VALU (distance, 4 partial sums) + exp + 64 fmac per j.
//   wave = 64 i x 16-j slice; block = 4 waves (64 j); grid = 8b x 8it x 8jg
//   = 512 blocks -> 2048 waves = 2/SIMD (fixes R3's 1-wave/SIMD cliff).
//   Cross-wave combine: waves 1..3 dump acc to LDS (XOR-swizzled float4
//   chunks -> conflict-free), wave 0 reduces and stores the block partial.
// k2: reduce 8 j-group partials per row + divide (unchanged from R2).

#define LAPLACE_SCALE 0.5f

constexpr int B_ = 8, M_ = 512, D_ = 64;
constexpr int GRID1 = 8 * 8 * 8;                 // 512 blocks
constexpr size_t REP_ELEMS = (size_t)GRID1 * 4096;

__global__ __launch_bounds__(256, 2)
void laplace_k1(const float* __restrict__ K, const float* __restrict__ V,
                float* __restrict__ rep_part, float* __restrict__ den_part) {
    __shared__ __align__(16) float comb[3][64][64];  // 48 KB
    __shared__ float denl[4][64];

    const int blk = blockIdx.x;
    const int b  = blk >> 6;
    const int it = (blk >> 3) & 7;
    const int jg = blk & 7;

    const float* __restrict__ Kb = K + (size_t)b * M_ * D_;
    const float* __restrict__ Vb = V + (size_t)b * M_ * D_;

    const int t = threadIdx.x;
    const int w = t >> 6, lane = t & 63;
    const int i = it * 64 + lane;

    // ---- lane-private V row and accumulator (registers) ----
    float vi[64], acc[64];
    {
        const float4* vip = reinterpret_cast<const float4*>(Vb + (size_t)i * D_);
#pragma unroll
        for (int c = 0; c < 16; ++c) {
            const float4 q = vip[c];
            vi[c * 4 + 0] = q.x; vi[c * 4 + 1] = q.y;
            vi[c * 4 + 2] = q.z; vi[c * 4 + 3] = q.w;
        }
    }
#pragma unroll
    for (int d = 0; d < 64; ++d) acc[d] = 0.f;
    float den = 0.f;

    // ---- main loop over this wave's 16 j's (uniform k/v rows) ----
    const int j0 = jg * 64 + w * 16;
#pragma unroll 2
    for (int jj = 0; jj < 16; ++jj) {
        const float* kr = Kb + (size_t)(j0 + jj) * D_;
        const float* vr = Vb + (size_t)(j0 + jj) * D_;

        float s0 = 0.f, s1 = 0.f, s2 = 0.f, s3 = 0.f;
#pragma unroll
        for (int c = 0; c < 16; ++c) {
            const float4 kq = *reinterpret_cast<const float4*>(kr + c * 4);
            s0 += fabsf(kq.x - vi[c * 4 + 0]);
            s1 += fabsf(kq.y - vi[c * 4 + 1]);
            s2 += fabsf(kq.z - vi[c * 4 + 2]);
            s3 += fabsf(kq.w - vi[c * 4 + 3]);
        }
        const float s = (s0 + s1) + (s2 + s3);
        const float wgt = __expf(s * LAPLACE_SCALE);
        den += wgt;
#pragma unroll
        for (int c = 0; c < 16; ++c) {
            const float4 vq = *reinterpret_cast<const float4*>(vr + c * 4);
            acc[c * 4 + 0] = fmaf(wgt, vq.x, acc[c * 4 + 0]);
            acc[c * 4 + 1] = fmaf(wgt, vq.y, acc[c * 4 + 1]);
            acc[c * 4 + 2] = fmaf(wgt, vq.z, acc[c * 4 + 2]);
            acc[c * 4 + 3] = fmaf(wgt, vq.w, acc[c * 4 + 3]);
        }
    }

    // ---- cross-wave combine (additive) ----
    denl[w][lane] = den;
    if (w > 0) {
        float4* dst = reinterpret_cast<float4*>(&comb[w - 1][lane][0]);
#pragma unroll
        for (int c4 = 0; c4 < 16; ++c4) {
            dst[c4 ^ (lane & 15)] =   // XOR swizzle: conflict-free banks
                make_float4(acc[c4 * 4 + 0], acc[c4 * 4 + 1],
                            acc[c4 * 4 + 2], acc[c4 * 4 + 3]);
        }
    }
    __syncthreads();
    if (w == 0) {
        float* rp = rep_part + (size_t)blk * 4096 + (size_t)lane * 64;
        const float4* s0 = reinterpret_cast<const float4*>(&comb[0][lane][0]);
        const float4* s1 = reinterpret_cast<const float4*>(&comb[1][lane][0]);
        const float4* s2 = reinterpret_cast<const float4*>(&comb[2][lane][0]);
#pragma unroll
        for (int c4 = 0; c4 < 16; ++c4) {
            const int p = c4 ^ (lane & 15);
            const float4 a0 = s0[p], a1 = s1[p], a2 = s2[p];
            reinterpret_cast<float4*>(rp)[c4] = make_float4(
                acc[c4 * 4 + 0] + a0.x + a1.x + a2.x,
                acc[c4 * 4 + 1] + a0.y + a1.y + a2.y,
                acc[c4 * 4 + 2] + a0.z + a1.z + a2.z,
                acc[c4 * 4 + 3] + a0.w + a1.w + a2.w);
        }
        den_part[(size_t)blk * 64 + lane] =
            denl[0][lane] + denl[1][lane] + denl[2][lane] + denl[3][lane];
    }
}

__global__ __launch_bounds__(256)
void laplace_k2(const float* __restrict__ rep_part,
                const float* __restrict__ den_part,
                float* __restrict__ out) {
    const int gid = blockIdx.x * 256 + threadIdx.x;   // 0 .. 262143
    const int b   = gid >> 15;
    const int i   = (gid >> 6) & 511;
    const int dd  = gid & 63;
    const int it  = i >> 6, il = i & 63;

    const size_t g = (size_t)(b * 8 + it) * 8;
    const float* rp = rep_part + g * 4096 + il * 64 + dd;
    const float* dp = den_part + g * 64 + il;
    float a = 0.f, dn = 0.f;
#pragma unroll
    for (int jt = 0; jt < 8; ++jt) {
        a  += rp[(size_t)jt * 4096];
        dn += dp[(size_t)jt * 64];
    }
    out[gid] = a / dn;
}

extern "C" void kernel_launch(void* const* d_in, const int* in_sizes, int n_in,
                              void* d_out, int out_size, void* d_ws, size_t ws_size,
                              hipStream_t stream) {
    const float* K = (const float*)d_in[0];
    const float* V = (const float*)d_in[1];
    float* out      = (float*)d_out;
    float* rep_part = (float*)d_ws;
    float* den_part = rep_part + REP_ELEMS;

    laplace_k1<<<dim3(GRID1), dim3(256), 0, stream>>>(K, V, rep_part, den_part);
    laplace_k2<<<dim3((B_ * M_ * D_) / 256), dim3(256), 0, stream>>>(rep_part, den_part, out);
}

// Round 5
// 30.097 us; speedup vs baseline: 2.6897x; 2.6897x over previous
//
#include <hip/hip_runtime.h>

// Laplace attention: unnorm[b,i,j] = sum_d |k[b,j,d] - v[b,i,d]| * 0.5
//                    W = softmax_j(unnorm);  out = W @ v[b]
// B=8, M=512, D=64, fp32. q unused. No max-subtraction needed (dist ~36+-3.4,
// exp fp32-safe) -> all partial combines purely additive.
//
// k1 (register-resident, two-pass, spill-free):
//   lane = output row i (64 i per wave). Wave owns a 16-j slice; j base is
//   SCALAR (blockIdx + readfirstlane(wave id)) so k[j]/v[j] row loads are
//   wave-uniform (s_load eligible). Pass A: va[64] = lane's V row; compute
//   dist -> wj[16] weights + den. Pass B: va[] reused as acc[64];
//   acc[d] += wj*v[j][d]. Peak live regs ~100 (R4 spilled at 128+).
//   Epilogue: 4-wave additive combine in LDS (stride-68 rows ~ b128 floor),
//   coalesced partial store. Grid 512 = 8b x 8it x 8jg, 256 thr -> 2 waves/
//   SIMD (R3's 1/SIMD latency cliff avoided).
// k2: reduce 8 j-group partials + divide.

#define LAPLACE_SCALE 0.5f

constexpr int B_ = 8, M_ = 512, D_ = 64;
constexpr int GRID1 = 8 * 8 * 8;                 // 512 blocks
constexpr size_t REP_ELEMS = (size_t)GRID1 * 4096;
constexpr int CSTR = 68;                         // comb row stride (floats)

__global__ __launch_bounds__(256, 2)
void laplace_k1(const float* __restrict__ K, const float* __restrict__ V,
                float* __restrict__ rep_part, float* __restrict__ den_part) {
    __shared__ __align__(16) float comb[4][64][CSTR];   // 69632 B
    __shared__ float cden[4][64];

    const int blk = blockIdx.x;
    const int b  = blk >> 6;
    const int it = (blk >> 3) & 7;
    const int jg = blk & 7;

    const float* __restrict__ Kb = K + (size_t)b * (M_ * D_);
    const float* __restrict__ Vb = V + (size_t)b * (M_ * D_);

    const int t    = threadIdx.x;
    const int lane = t & 63;
    const int wu   = __builtin_amdgcn_readfirstlane(t >> 6);  // scalar wave id

    const int i  = it * 64 + lane;
    const int j0 = jg * 64 + wu * 16;

    // ---- pass A: va = lane's V row; distance + exp -> wj[16], den ----
    float va[64];
    {
        const float4* vp = reinterpret_cast<const float4*>(Vb + (size_t)i * D_);
#pragma unroll
        for (int c = 0; c < 16; ++c) {
            const float4 q = vp[c];
            va[4 * c + 0] = q.x; va[4 * c + 1] = q.y;
            va[4 * c + 2] = q.z; va[4 * c + 3] = q.w;
        }
    }
    float wj[16];
    float den = 0.f;
#pragma unroll
    for (int jj = 0; jj < 16; ++jj) {
        const float* kr = Kb + (size_t)(j0 + jj) * D_;   // wave-uniform row
        float s0 = 0.f, s1 = 0.f, s2 = 0.f, s3 = 0.f;
#pragma unroll
        for (int c = 0; c < 16; ++c) {
            const float4 kq = *reinterpret_cast<const float4*>(kr + 4 * c);
            s0 += fabsf(kq.x - va[4 * c + 0]);
            s1 += fabsf(kq.y - va[4 * c + 1]);
            s2 += fabsf(kq.z - va[4 * c + 2]);
            s3 += fabsf(kq.w - va[4 * c + 3]);
        }
        const float w = __expf(((s0 + s1) + (s2 + s3)) * LAPLACE_SCALE);
        wj[jj] = w;
        den += w;
    }

    // ---- pass B: reuse va as PV accumulator ----
#pragma unroll
    for (int d = 0; d < 64; ++d) va[d] = 0.f;
#pragma unroll
    for (int jj = 0; jj < 16; ++jj) {
        const float* vr = Vb + (size_t)(j0 + jj) * D_;   // wave-uniform row
        const float w = wj[jj];
#pragma unroll
        for (int c = 0; c < 16; ++c) {
            const float4 vq = *reinterpret_cast<const float4*>(vr + 4 * c);
            va[4 * c + 0] = fmaf(w, vq.x, va[4 * c + 0]);
            va[4 * c + 1] = fmaf(w, vq.y, va[4 * c + 1]);
            va[4 * c + 2] = fmaf(w, vq.z, va[4 * c + 2]);
            va[4 * c + 3] = fmaf(w, vq.w, va[4 * c + 3]);
        }
    }

    // ---- cross-wave additive combine in LDS ----
    {
        float4* dst = reinterpret_cast<float4*>(&comb[wu][lane][0]);
#pragma unroll
        for (int c = 0; c < 16; ++c)
            dst[c] = make_float4(va[4 * c + 0], va[4 * c + 1],
                                 va[4 * c + 2], va[4 * c + 3]);
        cden[wu][lane] = den;
    }
    __syncthreads();

    // ---- coalesced reduce + store: thread t -> 16 consecutive floats ----
    {
        const int i2 = t >> 2;            // 0..63
        const int d0 = (t & 3) * 16;
        float* rp = rep_part + (size_t)blk * 4096 + (size_t)i2 * 64 + d0;
#pragma unroll
        for (int c4 = 0; c4 < 4; ++c4) {
            const int off = d0 + 4 * c4;
            const float4 a0 = *reinterpret_cast<const float4*>(&comb[0][i2][off]);
            const float4 a1 = *reinterpret_cast<const float4*>(&comb[1][i2][off]);
            const float4 a2 = *reinterpret_cast<const float4*>(&comb[2][i2][off]);
            const float4 a3 = *reinterpret_cast<const float4*>(&comb[3][i2][off]);
            reinterpret_cast<float4*>(rp)[c4] = make_float4(
                (a0.x + a1.x) + (a2.x + a3.x),
                (a0.y + a1.y) + (a2.y + a3.y),
                (a0.z + a1.z) + (a2.z + a3.z),
                (a0.w + a1.w) + (a2.w + a3.w));
        }
        if (t < 64)
            den_part[(size_t)blk * 64 + t] =
                (cden[0][t] + cden[1][t]) + (cden[2][t] + cden[3][t]);
    }
}

__global__ __launch_bounds__(256)
void laplace_k2(const float* __restrict__ rep_part,
                const float* __restrict__ den_part,
                float* __restrict__ out) {
    const int gid = blockIdx.x * 256 + threadIdx.x;   // 0 .. 262143
    const int b   = gid >> 15;
    const int i   = (gid >> 6) & 511;
    const int dd  = gid & 63;
    const int it  = i >> 6, il = i & 63;

    const size_t g = (size_t)(b * 8 + it) * 8;
    const float* rp = rep_part + g * 4096 + (size_t)il * 64 + dd;
    const float* dp = den_part + g * 64 + il;
    float a = 0.f, dn = 0.f;
#pragma unroll
    for (int jt = 0; jt < 8; ++jt) {
        a  += rp[(size_t)jt * 4096];
        dn += dp[(size_t)jt * 64];
    }
    out[gid] = a / dn;
}

extern "C" void kernel_launch(void* const* d_in, const int* in_sizes, int n_in,
                              void* d_out, int out_size, void* d_ws, size_t ws_size,
                              hipStream_t stream) {
    const float* K = (const float*)d_in[0];
    const float* V = (const float*)d_in[1];
    float* out      = (float*)d_out;
    float* rep_part = (float*)d_ws;
    float* den_part = rep_part + REP_ELEMS;

    laplace_k1<<<dim3(GRID1), dim3(256), 0, stream>>>(K, V, rep_part, den_part);
    laplace_k2<<<dim3((B_ * M_ * D_) / 256), dim3(256), 0, stream>>>(rep_part, den_part, out);
}

// Round 6
// 23.637 us; speedup vs baseline: 3.4248x; 1.2733x over previous
//
#include <hip/hip_runtime.h>

// Laplace attention: unnorm[b,i,j] = sum_d |k[b,j,d] - v[b,i,d]| * 0.5
//                    W = softmax_j(unnorm);  out = W @ v[b]
// B=8, M=512, D=64, fp32. q unused.
//
// R6: fp16-packed operands + v_dot2_f32_f16 (f32 accumulation).
//   k1: grid 512 = b x it x jt, block 256 (4 waves) = 64i x 64j tile.
//     distance: lane 4i x 4j tile; operands packed over d-pairs (h2) ->
//       per d2: 2 ds_read_b128, 48 VALU (pk_sub + packed-abs + fdot2).
//     softmax: per-block row max m (shfl + cross-wave LDS exchange) ->
//       w = exp(0.5*(s - m)) <= 1 -> f16-safe. den per row. m,den -> ws.
//     PV: w packed over j-pairs into wH[j2][i]; V packed over j-pairs in
//       vJ2[j2][d]; acc(i,d) f32 += dot2(w2, v2). lane 4i x 4d.
//   k2: flash-style combine over 8 jt blocks: M=max m, f=exp(m-M),
//       out = sum f*rep / sum f*den.

typedef _Float16 h2 __attribute__((ext_vector_type(2)));

#if __has_builtin(__builtin_amdgcn_fdot2)
#define FDOT2(a, b, c) __builtin_amdgcn_fdot2((a), (b), (c), false)
#else
static __device__ inline float FDOT2(h2 a, h2 b, float c) {
    return c + (float)a.x * (float)b.x + (float)a.y * (float)b.y;
}
#endif

static __device__ inline unsigned pk16(float x, float y) {   // RTNE pack
    h2 h;
    h.x = (_Float16)x;
    h.y = (_Float16)y;
    return __builtin_bit_cast(unsigned, h);
}

constexpr int B_ = 8, M_ = 512, D_ = 64;
constexpr int GRID1 = 8 * 8 * 8;                  // 512
constexpr size_t REP_ELEMS = (size_t)GRID1 * 4096;

// LDS u32 offsets: four [32][68] buffers
constexpr int OFF_VH  = 0;        // vH[d2][i]  (V i-rows, d-pair packed)
constexpr int OFF_KH  = 2176;     // kH[d2][j]  (K j-rows, d-pair packed)
constexpr int OFF_VJ2 = 4352;     // vJ2[j2][d] (V j-rows, j-pair packed)
constexpr int OFF_WH  = 6528;     // wH[j2][i]  (weights, j-pair packed)
constexpr int LDS_U   = 8704;

__global__ __launch_bounds__(256, 2)
void laplace_k1(const float* __restrict__ K, const float* __restrict__ V,
                float* __restrict__ rep_part, float2* __restrict__ md_part) {
    __shared__ __align__(16) unsigned ldsU[LDS_U];
    __shared__ __align__(16) float mrow[2][64];
    __shared__ __align__(16) float den_lds[2][64];

    const int blk = blockIdx.x;
    const int b  = blk >> 6;
    const int it = (blk >> 3) & 7;
    const int jt = blk & 7;
    const int i0 = it * 64, j0 = jt * 64;

    const float* __restrict__ Kb = K + (size_t)b * (M_ * D_);
    const float* __restrict__ Vb = V + (size_t)b * (M_ * D_);

    const int t = threadIdx.x;

    // ---------------- stage ----------------
    {   // vH, kH: row (i or j), packed over d-pairs
        const int row = t >> 2;
        const int dq  = t & 3;                    // 16-d chunk
        const float* vp = Vb + (size_t)(i0 + row) * D_ + dq * 16;
        const float* kp = Kb + (size_t)(j0 + row) * D_ + dq * 16;
#pragma unroll
        for (int c = 0; c < 4; ++c) {
            const float4 vq = *reinterpret_cast<const float4*>(vp + 4 * c);
            const float4 kq = *reinterpret_cast<const float4*>(kp + 4 * c);
            const int d2 = dq * 8 + 2 * c;
            ldsU[OFF_VH + (d2 + 0) * 68 + row] = pk16(vq.x, vq.y);
            ldsU[OFF_VH + (d2 + 1) * 68 + row] = pk16(vq.z, vq.w);
            ldsU[OFF_KH + (d2 + 0) * 68 + row] = pk16(kq.x, kq.y);
            ldsU[OFF_KH + (d2 + 1) * 68 + row] = pk16(kq.z, kq.w);
        }
    }
    {   // vJ2: packed over j-pairs at fixed d
        const int j2 = t >> 3;                    // 0..31
        const int dc = (t & 7) * 8;               // 8-d chunk
        const float* r0 = Vb + (size_t)(j0 + 2 * j2) * D_ + dc;
        const float* r1 = r0 + D_;
        unsigned o[8];
#pragma unroll
        for (int c = 0; c < 8; c += 4) {
            const float4 a = *reinterpret_cast<const float4*>(r0 + c);
            const float4 bq = *reinterpret_cast<const float4*>(r1 + c);
            o[c + 0] = pk16(a.x, bq.x);
            o[c + 1] = pk16(a.y, bq.y);
            o[c + 2] = pk16(a.z, bq.z);
            o[c + 3] = pk16(a.w, bq.w);
        }
        *reinterpret_cast<uint4*>(&ldsU[OFF_VJ2 + j2 * 68 + dc]) =
            make_uint4(o[0], o[1], o[2], o[3]);
        *reinterpret_cast<uint4*>(&ldsU[OFF_VJ2 + j2 * 68 + dc + 4]) =
            make_uint4(o[4], o[5], o[6], o[7]);
    }
    __syncthreads();

    // ---------------- distance ----------------
    const int wv = t >> 6, lane = t & 63;
    const int wi = wv >> 1, wj = wv & 1;
    const int ig = lane >> 3, jg = lane & 7;
    const int iQ = wi * 32 + ig * 4;
    const int jQ = wj * 32 + jg * 4;

    const h2 kOnes = {(_Float16)1.0f, (_Float16)1.0f};

    float s[4][4];
#pragma unroll
    for (int a = 0; a < 4; ++a)
#pragma unroll
        for (int b2 = 0; b2 < 4; ++b2) s[a][b2] = 0.f;

#pragma unroll 4
    for (int d2 = 0; d2 < 32; ++d2) {
        const uint4 va = *reinterpret_cast<const uint4*>(&ldsU[OFF_VH + d2 * 68 + iQ]);
        const uint4 ka = *reinterpret_cast<const uint4*>(&ldsU[OFF_KH + d2 * 68 + jQ]);
        const unsigned vaA[4] = {va.x, va.y, va.z, va.w};
        const unsigned kaA[4] = {ka.x, ka.y, ka.z, ka.w};
#pragma unroll
        for (int a = 0; a < 4; ++a) {
            const h2 vv = __builtin_bit_cast(h2, vaA[a]);
#pragma unroll
            for (int b2 = 0; b2 < 4; ++b2) {
                const h2 kk = __builtin_bit_cast(h2, kaA[b2]);
                const h2 df = kk - vv;                              // v_pk_add_f16
                const unsigned ad =
                    __builtin_bit_cast(unsigned, df) & 0x7FFF7FFFu; // packed abs
                s[a][b2] = FDOT2(__builtin_bit_cast(h2, ad), kOnes, s[a][b2]);
            }
        }
    }

    // ---------------- softmax (block-level row max) ----------------
    float rm[4];
#pragma unroll
    for (int a = 0; a < 4; ++a) {
        rm[a] = fmaxf(fmaxf(s[a][0], s[a][1]), fmaxf(s[a][2], s[a][3]));
        rm[a] = fmaxf(rm[a], __shfl_xor(rm[a], 1));
        rm[a] = fmaxf(rm[a], __shfl_xor(rm[a], 2));
        rm[a] = fmaxf(rm[a], __shfl_xor(rm[a], 4));
    }
    if (jg == 0)
        *reinterpret_cast<float4*>(&mrow[wj][iQ]) =
            make_float4(rm[0], rm[1], rm[2], rm[3]);
    __syncthreads();
    const float4 mo = *reinterpret_cast<const float4*>(&mrow[wj ^ 1][iQ]);
    const float m[4] = {fmaxf(rm[0], mo.x), fmaxf(rm[1], mo.y),
                        fmaxf(rm[2], mo.z), fmaxf(rm[3], mo.w)};

    float wgt[4][4], dn[4];
#pragma unroll
    for (int a = 0; a < 4; ++a) {
        dn[a] = 0.f;
#pragma unroll
        for (int b2 = 0; b2 < 4; ++b2) {
            const float e = __expf(0.5f * (s[a][b2] - m[a]));
            wgt[a][b2] = e;
            dn[a] += e;
        }
        dn[a] += __shfl_xor(dn[a], 1);
        dn[a] += __shfl_xor(dn[a], 2);
        dn[a] += __shfl_xor(dn[a], 4);
    }
    if (jg == 0)
        *reinterpret_cast<float4*>(&den_lds[wj][iQ]) =
            make_float4(dn[0], dn[1], dn[2], dn[3]);

    // pack weights over j-pairs -> wH[j2][i]
#pragma unroll
    for (int p = 0; p < 2; ++p) {
        const unsigned w0 = pk16(wgt[0][2 * p], wgt[0][2 * p + 1]);
        const unsigned w1 = pk16(wgt[1][2 * p], wgt[1][2 * p + 1]);
        const unsigned w2 = pk16(wgt[2][2 * p], wgt[2][2 * p + 1]);
        const unsigned w3 = pk16(wgt[3][2 * p], wgt[3][2 * p + 1]);
        *reinterpret_cast<uint4*>(
            &ldsU[OFF_WH + (wj * 16 + jg * 2 + p) * 68 + iQ]) =
            make_uint4(w0, w1, w2, w3);
    }
    __syncthreads();

    // ---------------- PV (dot2 over j-pairs) ----------------
    const int li4 = lane >> 4;          // 0..3
    const int dg  = lane & 15;          // 0..15
    const int ip  = wv * 16 + li4 * 4;  // i base (wave owns 16 i)
    const int dp  = dg * 4;             // d base

    float acc[4][4];
#pragma unroll
    for (int a = 0; a < 4; ++a)
#pragma unroll
        for (int c = 0; c < 4; ++c) acc[a][c] = 0.f;

#pragma unroll 4
    for (int j2 = 0; j2 < 32; ++j2) {
        const uint4 wq = *reinterpret_cast<const uint4*>(&ldsU[OFF_WH + j2 * 68 + ip]);
        const uint4 vq = *reinterpret_cast<const uint4*>(&ldsU[OFF_VJ2 + j2 * 68 + dp]);
        const unsigned wA[4] = {wq.x, wq.y, wq.z, wq.w};
        const unsigned vA[4] = {vq.x, vq.y, vq.z, vq.w};
#pragma unroll
        for (int a = 0; a < 4; ++a) {
            const h2 wa = __builtin_bit_cast(h2, wA[a]);
#pragma unroll
            for (int c = 0; c < 4; ++c)
                acc[a][c] = FDOT2(wa, __builtin_bit_cast(h2, vA[c]), acc[a][c]);
        }
    }

    // ---------------- store partials ----------------
    float* rp = rep_part + (size_t)blk * 4096;
#pragma unroll
    for (int a = 0; a < 4; ++a)
        *reinterpret_cast<float4*>(&rp[(ip + a) * 64 + dp]) =
            make_float4(acc[a][0], acc[a][1], acc[a][2], acc[a][3]);

    if (t < 64) {
        const float m_i = fmaxf(mrow[0][t], mrow[1][t]) * 0.5f;
        const float d_i = den_lds[0][t] + den_lds[1][t];
        md_part[(size_t)blk * 64 + t] = make_float2(m_i, d_i);
    }
}

__global__ __launch_bounds__(256)
void laplace_k2(const float* __restrict__ rep_part,
                const float2* __restrict__ md_part,
                float* __restrict__ out) {
    const int gid = blockIdx.x * 256 + threadIdx.x;   // 0 .. 262143
    const int b   = gid >> 15;
    const int i   = (gid >> 6) & 511;
    const int dd  = gid & 63;
    const int it  = i >> 6, il = i & 63;

    const size_t g = (size_t)(b * 8 + it) * 8;

    float2 md[8];
#pragma unroll
    for (int jt = 0; jt < 8; ++jt) md[jt] = md_part[(g + jt) * 64 + il];

    float M = md[0].x;
#pragma unroll
    for (int jt = 1; jt < 8; ++jt) M = fmaxf(M, md[jt].x);

    float acc = 0.f, dsum = 0.f;
    const float* rp = rep_part + g * 4096 + (size_t)il * 64 + dd;
#pragma unroll
    for (int jt = 0; jt < 8; ++jt) {
        const float f = __expf(md[jt].x - M);
        dsum += f * md[jt].y;
        acc  += f * rp[(size_t)jt * 4096];
    }
    out[gid] = acc / dsum;
}

extern "C" void kernel_launch(void* const* d_in, const int* in_sizes, int n_in,
                              void* d_out, int out_size, void* d_ws, size_t ws_size,
                              hipStream_t stream) {
    const float* K = (const float*)d_in[0];
    const float* V = (const float*)d_in[1];
    float* out      = (float*)d_out;
    float* rep_part = (float*)d_ws;
    float2* md_part = (float2*)(rep_part + REP_ELEMS);

    laplace_k1<<<dim3(GRID1), dim3(256), 0, stream>>>(K, V, rep_part, md_part);
    laplace_k2<<<dim3((B_ * M_ * D_) / 256), dim3(256), 0, stream>>>(
        rep_part, md_part, out);
}

// Round 7
// 20.177 us; speedup vs baseline: 4.0122x; 1.1715x over previous
//
#include <hip/hip_runtime.h>

// Laplace attention: unnorm[b,i,j] = sum_d |k[b,j,d] - v[b,i,d]| * 0.5
//                    W = softmax_j(unnorm);  out = W @ v[b]
// B=8, M=512, D=64, fp32. q unused.
//
// R7: occupancy fix (4 waves/SIMD) + v_sad_u16 integer distance.
//   k1: grid 1024 = 8b x 16it x 8jg; block 256 thr (4 waves) = 32i x 64j.
//     K/V distance operands quantized to biased u16 (scale 4096, exact
//     integer |a-b|, quant err ~8e-4 on exp arg). Distance: per d-pair ONE
//     v_sad_u16 per (i,j)-pair; lane tile 2i x 4j; wave = 32i x 16j.
//     Softmax: block row-max (shfl + LDS exchange), w = exp2(s2 - m2) <= 1
//     -> f16-safe. PV: f16 dot2 over j-pairs; wave = 32i x 16d slice,
//     lane 4i x 2d. Partials (j-split 8) -> ws.
//   k2: flash combine over 8 jt partials (max/rescale/normalize).

typedef _Float16 h2 __attribute__((ext_vector_type(2)));

#if __has_builtin(__builtin_amdgcn_fdot2)
#define FDOT2(a, b, c) __builtin_amdgcn_fdot2((a), (b), (c), false)
#else
static __device__ inline float FDOT2(h2 a, h2 b, float c) {
    return c + (float)a.x * (float)b.x + (float)a.y * (float)b.y;
}
#endif

#if __has_builtin(__builtin_amdgcn_sad_u16)
#define SADU16(a, b, c) __builtin_amdgcn_sad_u16((a), (b), (c))
#else
static __device__ inline unsigned SADU16(unsigned a, unsigned b, unsigned c) {
    const unsigned al = a & 0xFFFFu, ah = a >> 16;
    const unsigned bl = b & 0xFFFFu, bh = b >> 16;
    const unsigned dl = al > bl ? al - bl : bl - al;
    const unsigned dh = ah > bh ? ah - bh : bh - ah;
    return c + dl + dh;
}
#endif

static __device__ inline unsigned pk16(float x, float y) {   // f32x2 -> f16x2
    h2 h;
    h.x = (_Float16)x;
    h.y = (_Float16)y;
    return __builtin_bit_cast(unsigned, h);
}

static __device__ inline unsigned q16(float x) {   // biased u16 quantize
    const float f = fminf(fmaxf(x * 4096.0f + 32768.5f, 0.5f), 65535.0f);
    return (unsigned)f;
}

constexpr int B_ = 8, M_ = 512, D_ = 64;
constexpr int GRID1 = 8 * 16 * 8;                 // 1024 blocks
constexpr size_t REP_ELEMS = (size_t)GRID1 * 2048;
// exp arg (log2): 0.5 * dist / ln2, dist = sad/4096
#define C2L 1.761099911e-4f

// LDS u32 offsets
constexpr int OFF_KH  = 0;      // [32 d2][68]  u16-pair K rows (j side)
constexpr int OFF_VH  = 2176;   // [32 d2][36]  u16-pair V rows (i side, 32 i)
constexpr int OFF_VJ2 = 3328;   // [32 j2][68]  f16-pair V (j-pairs) for PV
constexpr int OFF_WH  = 5504;   // [32 j2][36]  f16-pair weights
constexpr int OFF_MR  = 6656;   // [4][32] f32 row max (log2 units)
constexpr int OFF_DEN = 6784;   // [4][32] f32 row den
constexpr int LDS_U   = 6912;   // 27648 B

__global__ __launch_bounds__(256, 4)
void laplace_k1(const float* __restrict__ K, const float* __restrict__ V,
                float* __restrict__ rep_part, float2* __restrict__ md_part) {
    __shared__ __align__(16) unsigned lds[LDS_U];

    const int blk = blockIdx.x;
    const int b  = blk >> 7;
    const int it = (blk >> 3) & 15;
    const int jg = blk & 7;
    const int i0 = it * 32, j0 = jg * 64;

    const float* __restrict__ Kb = K + (size_t)b * (M_ * D_);
    const float* __restrict__ Vb = V + (size_t)b * (M_ * D_);

    const int t = threadIdx.x;

    // ---------------- stage ----------------
    {   // kH: 64 K rows, u16-pairs. row = t>>2, 16 floats at (t&3)*16
        const int row = t >> 2, dq = t & 3;
        const float* kp = Kb + (size_t)(j0 + row) * D_ + dq * 16;
#pragma unroll
        for (int c = 0; c < 4; ++c) {
            const float4 q = *reinterpret_cast<const float4*>(kp + 4 * c);
            lds[OFF_KH + (dq * 8 + 2 * c + 0) * 68 + row] = q16(q.x) | (q16(q.y) << 16);
            lds[OFF_KH + (dq * 8 + 2 * c + 1) * 68 + row] = q16(q.z) | (q16(q.w) << 16);
        }
    }
    {   // vH: 32 V rows (i side). row = t>>3, 8 floats at (t&7)*8
        const int row = t >> 3, dq = t & 7;
        const float* vp = Vb + (size_t)(i0 + row) * D_ + dq * 8;
        const float4 a = *reinterpret_cast<const float4*>(vp);
        const float4 c4 = *reinterpret_cast<const float4*>(vp + 4);
        lds[OFF_VH + (dq * 4 + 0) * 36 + row] = q16(a.x)  | (q16(a.y)  << 16);
        lds[OFF_VH + (dq * 4 + 1) * 36 + row] = q16(a.z)  | (q16(a.w)  << 16);
        lds[OFF_VH + (dq * 4 + 2) * 36 + row] = q16(c4.x) | (q16(c4.y) << 16);
        lds[OFF_VH + (dq * 4 + 3) * 36 + row] = q16(c4.z) | (q16(c4.w) << 16);
    }
    {   // vJ2: V j-rows packed over j-pairs (f16) for PV
        const int j2 = t >> 3;                    // 0..31
        const int dc = (t & 7) * 8;               // 8-d chunk
        const float* r0 = Vb + (size_t)(j0 + 2 * j2) * D_ + dc;
        const float* r1 = r0 + D_;
        unsigned o[8];
#pragma unroll
        for (int c = 0; c < 8; c += 4) {
            const float4 a = *reinterpret_cast<const float4*>(r0 + c);
            const float4 bq = *reinterpret_cast<const float4*>(r1 + c);
            o[c + 0] = pk16(a.x, bq.x);
            o[c + 1] = pk16(a.y, bq.y);
            o[c + 2] = pk16(a.z, bq.z);
            o[c + 3] = pk16(a.w, bq.w);
        }
        *reinterpret_cast<uint4*>(&lds[OFF_VJ2 + j2 * 68 + dc]) =
            make_uint4(o[0], o[1], o[2], o[3]);
        *reinterpret_cast<uint4*>(&lds[OFF_VJ2 + j2 * 68 + dc + 4]) =
            make_uint4(o[4], o[5], o[6], o[7]);
    }
    __syncthreads();

    // ---------------- distance (v_sad_u16) ----------------
    const int wv = t >> 6, lane = t & 63;
    const int ig = lane >> 2;      // i = ig*2   (0..15)
    const int jq = lane & 3;       // j = wv*16 + jq*4

    unsigned sacc[2][4];
#pragma unroll
    for (int a = 0; a < 2; ++a)
#pragma unroll
        for (int c = 0; c < 4; ++c) sacc[a][c] = 0u;

    const unsigned* pV = lds + OFF_VH + ig * 2;
    const unsigned* pK = lds + OFF_KH + wv * 16 + jq * 4;

#pragma unroll 8
    for (int d2 = 0; d2 < 32; ++d2) {
        const uint2 va = *reinterpret_cast<const uint2*>(pV + d2 * 36);
        const uint4 ka = *reinterpret_cast<const uint4*>(pK + d2 * 68);
        sacc[0][0] = SADU16(ka.x, va.x, sacc[0][0]);
        sacc[0][1] = SADU16(ka.y, va.x, sacc[0][1]);
        sacc[0][2] = SADU16(ka.z, va.x, sacc[0][2]);
        sacc[0][3] = SADU16(ka.w, va.x, sacc[0][3]);
        sacc[1][0] = SADU16(ka.x, va.y, sacc[1][0]);
        sacc[1][1] = SADU16(ka.y, va.y, sacc[1][1]);
        sacc[1][2] = SADU16(ka.z, va.y, sacc[1][2]);
        sacc[1][3] = SADU16(ka.w, va.y, sacc[1][3]);
    }

    // ---------------- softmax (block row-max, log2 domain) ----------------
    float sf[2][4];
#pragma unroll
    for (int a = 0; a < 2; ++a)
#pragma unroll
        for (int c = 0; c < 4; ++c) sf[a][c] = (float)sacc[a][c] * C2L;

    float rm[2];
#pragma unroll
    for (int a = 0; a < 2; ++a) {
        rm[a] = fmaxf(fmaxf(sf[a][0], sf[a][1]), fmaxf(sf[a][2], sf[a][3]));
        rm[a] = fmaxf(rm[a], __shfl_xor(rm[a], 1));
        rm[a] = fmaxf(rm[a], __shfl_xor(rm[a], 2));
    }
    float* mr = reinterpret_cast<float*>(lds + OFF_MR);
    float* dnl = reinterpret_cast<float*>(lds + OFF_DEN);
    if (jq == 0)
        *reinterpret_cast<float2*>(&mr[wv * 32 + ig * 2]) = make_float2(rm[0], rm[1]);
    __syncthreads();

    float m[2];
    {
        const float2 m0 = *reinterpret_cast<const float2*>(&mr[0 * 32 + ig * 2]);
        const float2 m1 = *reinterpret_cast<const float2*>(&mr[1 * 32 + ig * 2]);
        const float2 m2 = *reinterpret_cast<const float2*>(&mr[2 * 32 + ig * 2]);
        const float2 m3 = *reinterpret_cast<const float2*>(&mr[3 * 32 + ig * 2]);
        m[0] = fmaxf(fmaxf(m0.x, m1.x), fmaxf(m2.x, m3.x));
        m[1] = fmaxf(fmaxf(m0.y, m1.y), fmaxf(m2.y, m3.y));
    }

    float w[2][4], den[2];
#pragma unroll
    for (int a = 0; a < 2; ++a) {
        den[a] = 0.f;
#pragma unroll
        for (int c = 0; c < 4; ++c) {
            w[a][c] = exp2f(sf[a][c] - m[a]);
            den[a] += w[a][c];
        }
        den[a] += __shfl_xor(den[a], 1);
        den[a] += __shfl_xor(den[a], 2);
    }
    if (jq == 0)
        *reinterpret_cast<float2*>(&dnl[wv * 32 + ig * 2]) = make_float2(den[0], den[1]);

    // pack weights over j-pairs -> wH[j2][i]
    {
        const int j2 = wv * 8 + jq * 2;
#pragma unroll
        for (int a = 0; a < 2; ++a) {
            lds[OFF_WH + (j2 + 0) * 36 + ig * 2 + a] = pk16(w[a][0], w[a][1]);
            lds[OFF_WH + (j2 + 1) * 36 + ig * 2 + a] = pk16(w[a][2], w[a][3]);
        }
    }
    __syncthreads();

    // ---------------- PV (f16 dot2 over j-pairs) ----------------
    const int ig2 = lane >> 3;          // i = ig2*4  (0..28)
    const int dg2 = lane & 7;           // d = wv*16 + dg2*2

    float acc[4][2];
#pragma unroll
    for (int a = 0; a < 4; ++a) { acc[a][0] = 0.f; acc[a][1] = 0.f; }

    const unsigned* pW  = lds + OFF_WH + ig2 * 4;
    const unsigned* pVJ = lds + OFF_VJ2 + wv * 16 + dg2 * 2;

#pragma unroll 8
    for (int j2 = 0; j2 < 32; ++j2) {
        const uint4 wq = *reinterpret_cast<const uint4*>(pW + j2 * 36);
        const uint2 vq = *reinterpret_cast<const uint2*>(pVJ + j2 * 68);
        const h2 v0 = __builtin_bit_cast(h2, vq.x);
        const h2 v1 = __builtin_bit_cast(h2, vq.y);
        const unsigned wA[4] = {wq.x, wq.y, wq.z, wq.w};
#pragma unroll
        for (int a = 0; a < 4; ++a) {
            const h2 wa = __builtin_bit_cast(h2, wA[a]);
            acc[a][0] = FDOT2(wa, v0, acc[a][0]);
            acc[a][1] = FDOT2(wa, v1, acc[a][1]);
        }
    }

    // ---------------- store partials ----------------
    float* rp = rep_part + (size_t)blk * 2048;
#pragma unroll
    for (int a = 0; a < 4; ++a)
        *reinterpret_cast<float2*>(&rp[(ig2 * 4 + a) * 64 + wv * 16 + dg2 * 2]) =
            make_float2(acc[a][0], acc[a][1]);

    if (t < 32) {
        const float mf = fmaxf(fmaxf(mr[t], mr[32 + t]), fmaxf(mr[64 + t], mr[96 + t]));
        const float df = (dnl[t] + dnl[32 + t]) + (dnl[64 + t] + dnl[96 + t]);
        md_part[(size_t)blk * 32 + t] = make_float2(mf, df);
    }
}

__global__ __launch_bounds__(256)
void laplace_k2(const float* __restrict__ rep_part,
                const float2* __restrict__ md_part,
                float* __restrict__ out) {
    const int gid = blockIdx.x * 256 + threadIdx.x;   // 0 .. 262143
    const int b   = gid >> 15;
    const int i   = (gid >> 6) & 511;
    const int dd  = gid & 63;
    const int it  = i >> 5, il = i & 31;

    const size_t base = (size_t)(b * 16 + it) * 8;

    float2 md[8];
#pragma unroll
    for (int jt = 0; jt < 8; ++jt) md[jt] = md_part[(base + jt) * 32 + il];

    float M = md[0].x;
#pragma unroll
    for (int jt = 1; jt < 8; ++jt) M = fmaxf(M, md[jt].x);

    float acc = 0.f, dsum = 0.f;
    const float* rp = rep_part + base * 2048 + (size_t)il * 64 + dd;
#pragma unroll
    for (int jt = 0; jt < 8; ++jt) {
        const float f = exp2f(md[jt].x - M);
        dsum += f * md[jt].y;
        acc  += f * rp[(size_t)jt * 2048];
    }
    out[gid] = acc / dsum;
}

extern "C" void kernel_launch(void* const* d_in, const int* in_sizes, int n_in,
                              void* d_out, int out_size, void* d_ws, size_t ws_size,
                              hipStream_t stream) {
    const float* K = (const float*)d_in[0];
    const float* V = (const float*)d_in[1];
    float* out      = (float*)d_out;
    float* rep_part = (float*)d_ws;
    float2* md_part = (float2*)(rep_part + REP_ELEMS);

    laplace_k1<<<dim3(GRID1), dim3(256), 0, stream>>>(K, V, rep_part, md_part);
    laplace_k2<<<dim3((B_ * M_ * D_) / 256), dim3(256), 0, stream>>>(
        rep_part, md_part, out);
}